// Round 2
// baseline (682.532 us; speedup 1.0000x reference)
//
#include <hip/hip_runtime.h>
#include <math.h>

#define SCALE_F   64.0f
#define MARGIN_F  0.4f
#define H_F       0.333f
#define EPS_F     1e-3f

// native 16B vector type (HIP's float4 is a struct; ext_vector_type works
// directly with the clang nontemporal builtins)
typedef float floatx4 __attribute__((ext_vector_type(4)));

// ---------------------------------------------------------------------------
// Kernel 1: out = logits * SCALE.
// Grid-stride, 2048 blocks x 256 threads (Guideline 11): each wave runs a
// loop with 4 independent 16B loads in flight (ILP), instead of 400k
// single-load waves each paying a full HBM latency with no overlap.
// Nontemporal: single-touch 819 MB total stream, zero reuse -> bypass caches.
// ---------------------------------------------------------------------------
__global__ __launch_bounds__(256) void adaface_scale_kernel(
    const floatx4* __restrict__ in, floatx4* __restrict__ out, int n4) {
    const int stride = (int)(gridDim.x * blockDim.x);
    int i = (int)(blockIdx.x * blockDim.x + threadIdx.x);

    // main loop: 4 independent loads issued before any store
    const int limit = n4 - 3 * stride;   // stride*4 ~= 2M << INT_MAX, safe
    for (; i < limit; i += 4 * stride) {
        floatx4 a = __builtin_nontemporal_load(&in[i]);
        floatx4 b = __builtin_nontemporal_load(&in[i + stride]);
        floatx4 c = __builtin_nontemporal_load(&in[i + 2 * stride]);
        floatx4 d = __builtin_nontemporal_load(&in[i + 3 * stride]);
        a *= SCALE_F; b *= SCALE_F; c *= SCALE_F; d *= SCALE_F;
        __builtin_nontemporal_store(a, &out[i]);
        __builtin_nontemporal_store(b, &out[i + stride]);
        __builtin_nontemporal_store(c, &out[i + 2 * stride]);
        __builtin_nontemporal_store(d, &out[i + 3 * stride]);
    }
    // tail
    for (; i < n4; i += stride) {
        floatx4 v = __builtin_nontemporal_load(&in[i]);
        v *= SCALE_F;
        __builtin_nontemporal_store(v, &out[i]);
    }
}

// ---------------------------------------------------------------------------
// Kernel 2 (unchanged, absmax was 0.0): one block, B threads (B=1024).
//  - clip norms -> safe_norms
//  - block reduction for mean / unbiased std (ddof=1)
//  - margin_scaler, g_angular, g_add
//  - gather original target logit, apply angular+additive margin
//  - overwrite out[row*C + label] with new_target * SCALE
// ---------------------------------------------------------------------------
__global__ __launch_bounds__(1024) void adaface_fixup_kernel(
    const float* __restrict__ logits,
    const float* __restrict__ norms,
    const int*   __restrict__ labels,
    float* __restrict__ out, int B, int C) {

    int row = threadIdx.x;
    bool active = (row < B);

    float sn = 0.0f;
    if (active) {
        sn = norms[row];
        sn = fminf(fmaxf(sn, 1e-3f), 100.0f);
    }

    // wave (64-lane) shuffle reduction of sum and sum-of-squares
    float v  = sn;
    float v2 = sn * sn;
    #pragma unroll
    for (int off = 32; off > 0; off >>= 1) {
        v  += __shfl_down(v,  off, 64);
        v2 += __shfl_down(v2, off, 64);
    }

    __shared__ float s_sum[16];   // up to 1024/64 waves
    __shared__ float s_sq[16];
    __shared__ float s_mean, s_std;

    int wave = threadIdx.x >> 6;
    int lane = threadIdx.x & 63;
    if (lane == 0) { s_sum[wave] = v; s_sq[wave] = v2; }
    __syncthreads();

    if (threadIdx.x == 0) {
        int nwaves = (blockDim.x + 63) >> 6;
        float tsum = 0.0f, tsq = 0.0f;
        for (int i = 0; i < nwaves; ++i) { tsum += s_sum[i]; tsq += s_sq[i]; }
        float mean = tsum / (float)B;
        float var  = (tsq - tsum * tsum / (float)B) / (float)(B - 1);
        s_mean = mean;
        s_std  = sqrtf(fmaxf(var, 0.0f));
    }
    __syncthreads();

    if (!active) return;

    float mean = s_mean;
    float stdv = s_std;

    float ms = (sn - mean) / (stdv + EPS_F) * H_F;
    ms = fminf(fmaxf(ms, -1.0f), 1.0f);

    float g_ang = -MARGIN_F * ms;
    float g_add =  MARGIN_F + MARGIN_F * ms;

    int lab = labels[row];
    long long pos = (long long)row * (long long)C + (long long)lab;
    float tl = logits[pos];

    float theta = acosf(tl) + g_ang;
    theta = fminf(fmaxf(theta, EPS_F), (float)M_PI - EPS_F);
    float nt = cosf(theta) - g_add;

    out[pos] = nt * SCALE_F;
}

extern "C" void kernel_launch(void* const* d_in, const int* in_sizes, int n_in,
                              void* d_out, int out_size, void* d_ws, size_t ws_size,
                              hipStream_t stream) {
    const float* logits = (const float*)d_in[0];
    const float* norms  = (const float*)d_in[1];
    const int*   labels = (const int*)d_in[2];
    float* out = (float*)d_out;

    int B = in_sizes[1];              // norms is [B,1]
    int C = in_sizes[0] / B;          // logits is [B,C]
    int n  = in_sizes[0];
    int n4 = n >> 2;                  // exact: B*C % 4 == 0

    const int threads = 256;
    int blocks = (n4 + threads - 1) / threads;
    if (blocks > 2048) blocks = 2048;   // grid-stride cap (Guideline 11)

    adaface_scale_kernel<<<blocks, threads, 0, stream>>>(
        (const floatx4*)logits, (floatx4*)out, n4);

    adaface_fixup_kernel<<<1, 1024, 0, stream>>>(logits, norms, labels, out, B, C);
}